// Round 7
// baseline (21.892 us; speedup 1.0000x reference)
//
#include <hip/hip_runtime.h>
#include <hip/hip_bf16.h>

// HeteroSoap via MFMA: c[s*4+n][ab] = sum_atoms f_sn * Y_ab is a 16x16 GEMM
// with K = N atoms.
// Stage 1: per-atom f(16, species one-hot) and Y(16) in bf16, staged in
// wave-private LDS as ONE dword tile [comp][atom]: lo16 = f, hi16 = Y.
// 16 ds_write_b32 + 4 ds_read_b128 per 64 atoms (round 6: 32 writes + 4
// reads serving only half the data). XOR swizzle (dword idx ^= (c&7)<<2)
// applied identically on write and read keeps writes conflict-free and
// read starts spread across bank groups while preserving 4-dword runs.
// Fragment atom<->k map identical to proven round-6 kernel (atom = 8g+e).
// cred reduction buffer aliases the tile (wave-private, used post-loop):
// LDS 16 KB -> 8 blocks/CU at grid 2048 = 32 waves/CU for latency hiding.
// Stage 2: 32-block tree reduce. Stage 3: Yr/Yi/nnl contraction.

typedef short short8 __attribute__((ext_vector_type(8)));
typedef float f32x4 __attribute__((ext_vector_type(4)));
typedef unsigned int uint4v __attribute__((ext_vector_type(4)));

__device__ __forceinline__ unsigned short bfu(float x) {
    __hip_bfloat16 h = __float2bfloat16(x);
    unsigned short s; __builtin_memcpy(&s, &h, 2); return s;
}

__global__ void __launch_bounds__(256) soap_accum(
    const float* __restrict__ coo, const int* __restrict__ numbers,
    int N, int nb, float* __restrict__ partials)
{
    __shared__ unsigned int lT[4][16][64];  // [wave][comp][atom] f|Y<<16, 16 KB

    const int lane = threadIdx.x & 63;
    const int w = threadIdx.x >> 6;
    const int g = lane >> 4;            // k-group
    const int comp = lane & 15;         // fragment index dim (A row / B col)

    unsigned int* lTw = &lT[w][0][0];

    // Loop-invariant read pointers. Swizzle s(c)=4*(c&7) preserves aligned
    // 4-dword runs; dword at idx q holds atom q^s(c) -> elems give atoms
    // 8g..8g+7 (frag 0/1) and 32+8g..+7 (frag 2/3) in order, same map A & B.
    const unsigned t4 = (unsigned)((comp & 7) << 2);
    const unsigned rb = (unsigned)(comp << 6);
    const uint4v* q0p = (const uint4v*)&lTw[rb + (( 8u * g)      ^ t4)];
    const uint4v* q1p = (const uint4v*)&lTw[rb + (( 8u * g + 4)  ^ t4)];
    const uint4v* q2p = (const uint4v*)&lTw[rb + ((32u + 8u * g)     ^ t4)];
    const uint4v* q3p = (const uint4v*)&lTw[rb + ((32u + 8u * g + 4) ^ t4)];

    f32x4 acc = {0.f, 0.f, 0.f, 0.f};

    const int stride = nb * 256;        // 4 waves x 64 atoms per block per iter
    for (int base = (blockIdx.x * 4 + w) * 64; base < N; base += stride) {
        int i = base + lane;
        int ic = i < N ? i : N - 1;
        float x = coo[3 * ic + 0] * 0.5f;   // xyz = coo / UNIT, UNIT = 2
        float y = coo[3 * ic + 1] * 0.5f;
        float z = coo[3 * ic + 2] * 0.5f;
        int num = numbers[ic];

        float r2 = x * x + y * y + z * z;
        float ds = sqrtf(r2);
        float t = 1.f - ds * (1.f / 3.f);
        float cut = (ds < 3.f) ? t * t : 0.f;
        float r = __expf(-0.5f * r2) * cut;
        if (i >= N) r = 0.f;                 // tail: zero f-row kills the atom

        float f0 = r, f1 = r * r2, f2 = f1 * r2, f3 = f2 * r2;

        // Solid harmonics, packed (L+1)x(L+1) row-major:
        const float Y00 = 0.28209479177387814f;
        float re11 = -0.34549414947133550f * x;
        float im11 = -0.34549414947133550f * y;
        float re10 =  0.48860251190291992f * z;
        float re22 = -1.11803398874989490f * (x * re11 - y * im11);
        float im22 = -1.11803398874989490f * (x * im11 + y * re11);
        float re21 =  2.23606797749978970f * z * re11;
        float im21 =  2.23606797749978970f * z * im11;
        float re20 =  1.93649167310370850f * (z * re10 - 0.16286750396763996f * r2);
        float re33 = -1.08012344973464350f * (x * re22 - y * im22);
        float im33 = -1.08012344973464350f * (x * im22 + y * re22);
        float re32 =  2.64575131106459070f * z * re22;
        float im32 =  2.64575131106459070f * z * im22;
        float re31 =  2.09165006633518890f * (z * re21 - 0.44721359549995793f * r2 * re11);
        float im31 =  2.09165006633518890f * (z * im21 - 0.44721359549995793f * r2 * im11);
        float re30 =  1.97202659436653870f * (z * re20 - 0.51639777949432220f * r2 * re10);

        unsigned short yb[16];
        yb[0] = bfu(Y00);  yb[1] = bfu(im11); yb[2]  = bfu(im22); yb[3]  = bfu(im33);
        yb[4] = bfu(re11); yb[5] = bfu(re10); yb[6]  = bfu(im21); yb[7]  = bfu(im32);
        yb[8] = bfu(re22); yb[9] = bfu(re21); yb[10] = bfu(re20); yb[11] = bfu(im31);
        yb[12] = bfu(re33); yb[13] = bfu(re32); yb[14] = bfu(re31); yb[15] = bfu(re30);

        unsigned short hb[4] = {bfu(f0), bfu(f1), bfu(f2), bfu(f3)};

        // Packed swizzled stores: lane owns atom-column `lane`, 16 dwords.
#pragma unroll
        for (int c = 0; c < 16; ++c) {
            unsigned v = ((unsigned)yb[c] << 16)
                       | (unsigned)((num == (c >> 2)) ? hb[c & 3] : (unsigned short)0);
            lTw[(c << 6) + (lane ^ ((c & 7) << 2))] = v;
        }

        // Wave-private tile: compiler orders the aliasing writes/reads.
        uint4v q0 = *q0p, q1 = *q1p, q2 = *q2p, q3 = *q3p;

        short8 A0, B0, A1, B1;
#pragma unroll
        for (int e = 0; e < 4; ++e) {
            A0[e]     = (short)(q0[e] & 0xffffu);
            A0[4 + e] = (short)(q1[e] & 0xffffu);
            B0[e]     = (short)(q0[e] >> 16);
            B0[4 + e] = (short)(q1[e] >> 16);
            A1[e]     = (short)(q2[e] & 0xffffu);
            A1[4 + e] = (short)(q3[e] & 0xffffu);
            B1[e]     = (short)(q2[e] >> 16);
            B1[4 + e] = (short)(q3[e] >> 16);
        }

        acc = __builtin_amdgcn_mfma_f32_16x16x32_bf16(A0, B0, acc, 0, 0, 0);
        acc = __builtin_amdgcn_mfma_f32_16x16x32_bf16(A1, B1, acc, 0, 0, 0);
    }

    // C/D layout (m89): lane, reg rr -> c[i=(lane>>4)*4+rr][j=lane&15].
    // Reuse this wave's (now idle, wave-private) tile as the reduce buffer.
    float* credw = (float*)&lT[w][0][0];
#pragma unroll
    for (int rr = 0; rr < 4; ++rr)
        credw[((lane >> 4) * 4 + rr) * 16 + (lane & 15)] = acc[rr];
    __syncthreads();

    int tt = threadIdx.x;
    partials[blockIdx.x * 256 + tt] =
        ((float*)&lT[0][0][0])[tt] + ((float*)&lT[1][0][0])[tt] +
        ((float*)&lT[2][0][0])[tt] + ((float*)&lT[3][0][0])[tt];
}

__global__ void __launch_bounds__(256) soap_reduce(
    const float* __restrict__ partials, int nb, float* __restrict__ p2)
{
    int t = threadIdx.x;
    float v = 0.f;
    for (int r = blockIdx.x; r < nb; r += 32)
        v += partials[r * 256 + t];
    p2[blockIdx.x * 256 + t] = v;
}

// p1[a,b,n,m,l] = sum_{j<=l} w_j c[b,m,l,j] c[a,n,l,j]   (w = 1 if j==l else 2)
// p2[a,b,n,m,l] = sum_{i<l}  2  c[b,m,i,l] c[a,n,i,l]
// out = (p1+p2) * nnl[n,m,l]
__global__ void __launch_bounds__(1024) soap_finalize(
    const float* __restrict__ p2, float* __restrict__ out)
{
    __shared__ float cs[256];
    int t = threadIdx.x;
    if (t < 256) {
        float v = 0.f;
#pragma unroll
        for (int b = 0; b < 32; ++b) v += p2[b * 256 + t];
        cs[t] = v;
    }
    __syncthreads();

    int l = t & 3, m = (t >> 2) & 3, n = (t >> 4) & 3, b = (t >> 6) & 3, a = (t >> 8) & 3;
    const float* cbm = &cs[(b * 4 + m) * 16];
    const float* can = &cs[(a * 4 + n) * 16];

    float v = 0.f;
    for (int j = 0; j <= l; ++j) {
        float wgt = (j == l) ? 1.f : 2.f;
        v += wgt * cbm[l * 4 + j] * can[l * 4 + j];
    }
    for (int i = 0; i < l; ++i)
        v += 2.f * cbm[i * 4 + l] * can[i * 4 + l];

    const float fact[7] = {1.f, 1.f, 2.f, 6.f, 24.f, 120.f, 720.f};
    float an = 1.0f / ((float)(2 * l + 1) * (float)(1 << (2 * n + l)) * fact[n] * fact[n + l]);
    float am = 1.0f / ((float)(2 * l + 1) * (float)(1 << (2 * m + l)) * fact[m] * fact[m + l]);
    out[t] = v * sqrtf(an * am);
}

extern "C" void kernel_launch(void* const* d_in, const int* in_sizes, int n_in,
                              void* d_out, int out_size, void* d_ws, size_t ws_size,
                              hipStream_t stream)
{
    const float* coo = (const float*)d_in[0];
    const int* numbers = (const int*)d_in[1];
    int N = in_sizes[1];                 // 1,000,000 atoms

    float* p2 = (float*)d_ws;            // [32*256] stage-2 partials
    float* partials = p2 + 32 * 256;     // [nb*256] stage-1 partials

    long cap = (long)(ws_size / 1024) - 33;
    int nb = (int)(cap < 32 ? 32 : (cap > 2048 ? 2048 : cap));

    hipLaunchKernelGGL(soap_accum, dim3(nb), dim3(256), 0, stream,
                       coo, numbers, N, nb, partials);
    hipLaunchKernelGGL(soap_reduce, dim3(32), dim3(256), 0, stream,
                       partials, nb, p2);
    hipLaunchKernelGGL(soap_finalize, dim3(1), dim3(1024), 0, stream,
                       p2, (float*)d_out);
}

// Round 8
// 19.162 us; speedup vs baseline: 1.1425x; 1.1425x over previous
//
#include <hip/hip_runtime.h>
#include <hip/hip_bf16.h>

// HeteroSoap via MFMA: c[s*4+n][ab] = sum_atoms f_sn * Y_ab = 16x16 GEMM, K=N.
// Round 8: round-6 data path (proven: short tiles [comp][atom], XOR swizzle,
// 32 ds_write_b16 + 4 ds_read_b128 per 64-atom chunk, same atom<->k map for
// A and B so MFMA k-order cancels) restructured as a fully-unrolled 3-stage
// software pipeline: T=4 chunks/wave (compile-time, grid fixed at 1024),
// double-buffered wave-private tiles. Schedule interleaves load[k+2] /
// harmonics+write[k+1] / read+MFMA[k] so the global-load latency and the
// LDS write->read roundtrip are hidden under real work. No barriers in loop.
// Evidence: rounds 5/6/7 showed occupancy DOWN + iters/wave UP = faster
// (19.1 @4 blocks/CU vs 23.1/21.9 @7-8) -> latency-bound, not throughput.

typedef short short8 __attribute__((ext_vector_type(8)));
typedef float f32x4 __attribute__((ext_vector_type(4)));

#define NB 1024
#define STRIDE (NB * 256)

__device__ __forceinline__ short bfc(float x) {
    __hip_bfloat16 h = __float2bfloat16(x);
    short s; __builtin_memcpy(&s, &h, 2); return s;
}

// Swizzled index into a [16][64] short tile: row=comp, col=atom.
#define SWZ(c, a) (((c) << 6) + ((a) ^ (((c) & 7) << 3)))

// ---- pipeline stage macros (all state in enclosing scope) ----------------
#define LOADC(K, CX, CY, CZ, CN) {                                          \
    int i_ = base0 + (K) * STRIDE;                                          \
    int ic_ = i_ < N ? i_ : N - 1;                                          \
    CX = coo[3 * ic_ + 0]; CY = coo[3 * ic_ + 1]; CZ = coo[3 * ic_ + 2];    \
    CN = (i_ < N) ? numbers[ic_] : -1;  /* -1 -> zero f-row, atom dead */   \
}

#define HW(P, CX, CY, CZ, CN) {                                             \
    float x = CX * 0.5f, y = CY * 0.5f, z = CZ * 0.5f;   /* coo / UNIT */   \
    float r2 = x * x + y * y + z * z;                                       \
    float dq = sqrtf(r2);                                                   \
    float tc = 1.f - dq * (1.f / 3.f);                                      \
    float cut = (dq < 3.f) ? tc * tc : 0.f;                                 \
    float rr = __expf(-0.5f * r2) * cut;                                    \
    float f0 = rr, f1 = rr * r2, f2 = f1 * r2, f3 = f2 * r2;                \
    const float Y00 = 0.28209479177387814f;                                 \
    float re11 = -0.34549414947133550f * x;                                 \
    float im11 = -0.34549414947133550f * y;                                 \
    float re10 =  0.48860251190291992f * z;                                 \
    float re22 = -1.11803398874989490f * (x * re11 - y * im11);             \
    float im22 = -1.11803398874989490f * (x * im11 + y * re11);             \
    float re21 =  2.23606797749978970f * z * re11;                          \
    float im21 =  2.23606797749978970f * z * im11;                          \
    float re20 =  1.93649167310370850f * (z * re10 - 0.16286750396763996f * r2); \
    float re33 = -1.08012344973464350f * (x * re22 - y * im22);             \
    float im33 = -1.08012344973464350f * (x * im22 + y * re22);             \
    float re32 =  2.64575131106459070f * z * re22;                          \
    float im32 =  2.64575131106459070f * z * im22;                          \
    float re31 =  2.09165006633518890f * (z * re21 - 0.44721359549995793f * r2 * re11); \
    float im31 =  2.09165006633518890f * (z * im21 - 0.44721359549995793f * r2 * im11); \
    float re30 =  1.97202659436653870f * (z * re20 - 0.51639777949432220f * r2 * re10); \
    short yv[16];                                                           \
    yv[0] = bfc(Y00);  yv[1] = bfc(im11); yv[2]  = bfc(im22); yv[3]  = bfc(im33); \
    yv[4] = bfc(re11); yv[5] = bfc(re10); yv[6]  = bfc(im21); yv[7]  = bfc(im32); \
    yv[8] = bfc(re22); yv[9] = bfc(re21); yv[10] = bfc(re20); yv[11] = bfc(im31); \
    yv[12] = bfc(re33); yv[13] = bfc(re32); yv[14] = bfc(re31); yv[15] = bfc(re30); \
    short hv[4] = {bfc(f0), bfc(f1), bfc(f2), bfc(f3)};                     \
    short* lA_ = &lT[w][P][0][0][0];                                        \
    short* lB_ = &lT[w][P][1][0][0];                                        \
    _Pragma("unroll")                                                       \
    for (int c = 0; c < 16; ++c) {                                          \
        lA_[SWZ(c, lane)] = (CN == (c >> 2)) ? hv[c & 3] : (short)0;        \
        lB_[SWZ(c, lane)] = yv[c];                                          \
    }                                                                       \
}

#define RM(P) {                                                             \
    short* lA_ = &lT[w][P][0][0][0];                                        \
    short* lB_ = &lT[w][P][1][0][0];                                        \
    short8 A0 = *(const short8*)(lA_ + r0);                                 \
    short8 A1 = *(const short8*)(lA_ + r1);                                 \
    short8 B0 = *(const short8*)(lB_ + r0);                                 \
    short8 B1 = *(const short8*)(lB_ + r1);                                 \
    acc = __builtin_amdgcn_mfma_f32_16x16x32_bf16(A0, B0, acc, 0, 0, 0);    \
    acc = __builtin_amdgcn_mfma_f32_16x16x32_bf16(A1, B1, acc, 0, 0, 0);    \
}

__global__ void __launch_bounds__(256) soap_accum4(
    const float* __restrict__ coo, const int* __restrict__ numbers,
    int N, float* __restrict__ partials)
{
    __shared__ short lT[4][2][2][16][64];  // [wave][phase][A|B][comp][atom] 32KB

    const int lane = threadIdx.x & 63;
    const int w = threadIdx.x >> 6;
    const int g = lane >> 4;
    const int comp = lane & 15;

    const int sw = (comp & 7) << 3, cb = comp << 6;
    const int r0 = cb + ((8 * g) ^ sw);        // frag elems e -> atom 8g+e
    const int r1 = cb + ((32 + 8 * g) ^ sw);   // frag elems e -> atom 32+8g+e

    f32x4 acc = {0.f, 0.f, 0.f, 0.f};
    const int base0 = (blockIdx.x * 4 + w) * 64 + lane;

    float x0, y0, z0, x1, y1, z1, x2, y2, z2, x3, y3, z3;
    int n0, n1, n2, n3;

    // 3-stage pipeline, fully unrolled (T=4 chunks, every wave identical):
    LOADC(0, x0, y0, z0, n0)
    LOADC(1, x1, y1, z1, n1)
    HW(0, x0, y0, z0, n0)          // W[0] -> tile0
    LOADC(2, x2, y2, z2, n2)
    HW(1, x1, y1, z1, n1)          // W[1] -> tile1   (hides W0->R0 latency)
    RM(0)                          // R+MFMA chunk 0  (tile0)
    LOADC(3, x3, y3, z3, n3)
    HW(0, x2, y2, z2, n2)          // W[2] -> tile0   (after R[0], in-order LDS)
    RM(1)                          // chunk 1 (tile1)
    HW(1, x3, y3, z3, n3)          // W[3] -> tile1
    RM(0)                          // chunk 2 (tile0)
    RM(1)                          // chunk 3 (tile1)

    // C/D layout (m89): lane, reg rr -> c[i=(lane>>4)*4+rr][j=lane&15].
    // Reuse this wave's (idle, wave-private) tile region as reduce buffer.
    float* credw = (float*)&lT[w][0][0][0][0];
#pragma unroll
    for (int rr = 0; rr < 4; ++rr)
        credw[((lane >> 4) * 4 + rr) * 16 + (lane & 15)] = acc[rr];
    __syncthreads();

    int tt = threadIdx.x;
    partials[blockIdx.x * 256 + tt] =
        ((float*)&lT[0][0][0][0][0])[tt] + ((float*)&lT[1][0][0][0][0])[tt] +
        ((float*)&lT[2][0][0][0][0])[tt] + ((float*)&lT[3][0][0][0][0])[tt];
}

__global__ void __launch_bounds__(256) soap_reduce(
    const float* __restrict__ partials, int nb, float* __restrict__ p2)
{
    int t = threadIdx.x;
    float v = 0.f;
    for (int r = blockIdx.x; r < nb; r += 32)
        v += partials[r * 256 + t];
    p2[blockIdx.x * 256 + t] = v;
}

// p1[a,b,n,m,l] = sum_{j<=l} w_j c[b,m,l,j] c[a,n,l,j]   (w = 1 if j==l else 2)
// p2[a,b,n,m,l] = sum_{i<l}  2  c[b,m,i,l] c[a,n,i,l]
// out = (p1+p2) * nnl[n,m,l]
__global__ void __launch_bounds__(1024) soap_finalize(
    const float* __restrict__ p2, float* __restrict__ out)
{
    __shared__ float cs[256];
    int t = threadIdx.x;
    if (t < 256) {
        float v = 0.f;
#pragma unroll
        for (int b = 0; b < 32; ++b) v += p2[b * 256 + t];
        cs[t] = v;
    }
    __syncthreads();

    int l = t & 3, m = (t >> 2) & 3, n = (t >> 4) & 3, b = (t >> 6) & 3, a = (t >> 8) & 3;
    const float* cbm = &cs[(b * 4 + m) * 16];
    const float* can = &cs[(a * 4 + n) * 16];

    float v = 0.f;
    for (int j = 0; j <= l; ++j) {
        float wgt = (j == l) ? 1.f : 2.f;
        v += wgt * cbm[l * 4 + j] * can[l * 4 + j];
    }
    for (int i = 0; i < l; ++i)
        v += 2.f * cbm[i * 4 + l] * can[i * 4 + l];

    const float fact[7] = {1.f, 1.f, 2.f, 6.f, 24.f, 120.f, 720.f};
    float an = 1.0f / ((float)(2 * l + 1) * (float)(1 << (2 * n + l)) * fact[n] * fact[n + l]);
    float am = 1.0f / ((float)(2 * l + 1) * (float)(1 << (2 * m + l)) * fact[m] * fact[m + l]);
    out[t] = v * sqrtf(an * am);
}

extern "C" void kernel_launch(void* const* d_in, const int* in_sizes, int n_in,
                              void* d_out, int out_size, void* d_ws, size_t ws_size,
                              hipStream_t stream)
{
    const float* coo = (const float*)d_in[0];
    const int* numbers = (const int*)d_in[1];
    int N = in_sizes[1];                 // 1,000,000 atoms

    float* p2 = (float*)d_ws;            // [32*256] stage-2 partials
    float* partials = p2 + 32 * 256;     // [NB*256] stage-1 partials
    // ws requirement: (8192 + 262144) * 4 B = 1.06 MB (observed ws >= 2 MB).

    hipLaunchKernelGGL(soap_accum4, dim3(NB), dim3(256), 0, stream,
                       coo, numbers, N, partials);
    hipLaunchKernelGGL(soap_reduce, dim3(32), dim3(256), 0, stream,
                       partials, NB, p2);
    hipLaunchKernelGGL(soap_finalize, dim3(1), dim3(1024), 0, stream,
                       p2, (float*)d_out);
}